// Round 8
// baseline (691.581 us; speedup 1.0000x reference)
//
#include <hip/hip_runtime.h>
#include <hip/hip_cooperative_groups.h>

namespace cg = cooperative_groups;

// Problem constants: G=8 graphs, N=1024 nodes, F=128 in-feat, H=256 hidden,
// L=4 layers, B=64 samples.
#define GG 8
#define NN 1024
#define FF 128
#define HH 256
#define LL 4
#define BB 64
#define MM (GG * NN)  // 8192 fused (g,n) rows
#define ELLCAP 96     // max nnz/row stored (binomial(1024,.02) max ~48)
#define NBLK 256      // cooperative grid: 1 block/CU -> co-residency trivial

// prep-phase virtual block ranges
#define PB_DET 1
#define PB_XS (PB_DET + 1024)   // xs f32->bf16: 262144 float4
#define PB_W (PB_XS + 1152)     // weights ->bf16 transposed: 294912 elems
#define PB_TOT (PB_W + 2048)    // ELL build: 8192 rows, 4/vblock

typedef __attribute__((ext_vector_type(8))) short bf16x8_t;  // 8 bf16 = 4 VGPR
typedef __attribute__((ext_vector_type(4))) float f32x4_t;   // MFMA acc

__device__ inline unsigned short f2bf(float f) {
  union { float f; unsigned u; } c;
  c.f = f;
  unsigned r = (c.u + 0x7fffu + ((c.u >> 16) & 1u)) >> 16;  // RNE
  return (unsigned short)r;
}
__device__ inline float bf2f(unsigned short u) {
  union { unsigned u; float f; } c;
  c.u = (unsigned)u << 16;
  return c.f;
}

struct KParams {
  const int* graph;
  const void* mask;
  const float* xs;
  const float* Adj;
  const float* W_in;
  const float* b_in;
  const float* Ws;
  const float* bs;
  float* out;
  float* X;             // f32 [MM][HH] final activations
  float* X0;            // f32 [MM][HH] residual
  unsigned short* Yb;   // bf16 [MM][HH]
  unsigned short* Xb;   // bf16 [MM][HH]
  unsigned short* xsb;  // bf16 [MM][FF]
  unsigned short* WinT; // bf16 [HH][FF]
  unsigned short* WsT;  // bf16 [LL][HH][HH] (transposed per layer)
  uint2* ell;           // [MM][ELLCAP]
  int* cntArr;          // [MM]
  int* flags;           // flags[0] = mask mode (0 bool / 1 int32 / 2 f32)
  float* partial;       // [BB][16][HH]
  float* cntbuf;        // [BB][16]
};

// ---------------------------------------------------------------------------
// One-shot-K bf16 MFMA GEMM tile (validated in R5): C = A[M][K] @ BT[HH][K]^T.
// 64x64 tile, 4 waves (2x2 of 32x32), whole K staged in LDS once,
// XOR-swizzle (slot k ^= row&7) kills the 512B-row-stride bank conflict.
template <int K, bool FUSED>
__device__ inline void gemm_tile(const unsigned short* __restrict__ A,
                                 const unsigned short* __restrict__ BT,
                                 const float* __restrict__ bias,
                                 unsigned short* __restrict__ Cb,
                                 float* __restrict__ Cf, uint4* smem, int vt,
                                 int t) {
  constexpr int KS = K / 8;  // 16B slots per row
  uint4* As4 = smem;
  uint4* Bs4 = smem + 64 * KS;
  const int lane = t & 63;
  const int w = t >> 6;
  const int wm = (w >> 1) * 32;
  const int wn = (w & 1) * 32;
  const int m0 = (vt >> 2) * 64;  // 128 mtiles
  const int n0 = (vt & 3) * 64;   // 4 ntiles
  const int lk = lane >> 4;
  const int lr = lane & 15;
  const uint4* __restrict__ Ag = (const uint4*)(A + (size_t)m0 * K);
  const uint4* __restrict__ Bg = (const uint4*)(BT + (size_t)n0 * K);
  __syncthreads();  // protect LDS reuse across vt iterations / phases
#pragma unroll
  for (int it = 0; it < K / 32; ++it) {
    const int c = it * 256 + t;
    const int row = c / KS;
    const int k = c % KS;
    const int slot = row * KS + (k ^ (row & 7));
    As4[slot] = Ag[c];
    Bs4[slot] = Bg[c];
  }
  __syncthreads();
  f32x4_t acc[2][2] = {};
#pragma unroll
  for (int ks = 0; ks < K / 32; ++ks) {
    const int q = ks * 4 + lk;
    const int ra0 = wm + lr, ra1 = wm + 16 + lr;
    const int rb0 = wn + lr, rb1 = wn + 16 + lr;
    const bf16x8_t a0 = *(const bf16x8_t*)(&As4[ra0 * KS + (q ^ (ra0 & 7))]);
    const bf16x8_t a1 = *(const bf16x8_t*)(&As4[ra1 * KS + (q ^ (ra1 & 7))]);
    const bf16x8_t b0 = *(const bf16x8_t*)(&Bs4[rb0 * KS + (q ^ (rb0 & 7))]);
    const bf16x8_t b1 = *(const bf16x8_t*)(&Bs4[rb1 * KS + (q ^ (rb1 & 7))]);
    acc[0][0] = __builtin_amdgcn_mfma_f32_16x16x32_bf16(a0, b0, acc[0][0], 0, 0, 0);
    acc[0][1] = __builtin_amdgcn_mfma_f32_16x16x32_bf16(a0, b1, acc[0][1], 0, 0, 0);
    acc[1][0] = __builtin_amdgcn_mfma_f32_16x16x32_bf16(a1, b0, acc[1][0], 0, 0, 0);
    acc[1][1] = __builtin_amdgcn_mfma_f32_16x16x32_bf16(a1, b1, acc[1][1], 0, 0, 0);
  }
#pragma unroll
  for (int rg = 0; rg < 2; ++rg)
#pragma unroll
    for (int cg = 0; cg < 2; ++cg)
#pragma unroll
      for (int j = 0; j < 4; ++j) {
        // verified C/D layout: col = lane&15, row = (lane>>4)*4 + reg
        const int row = m0 + wm + rg * 16 + (lane >> 4) * 4 + j;
        const int col = n0 + wn + cg * 16 + lr;
        float v = acc[rg][cg][j];
        if (FUSED) {
          v += bias[col];
          v = fmaxf(v, 0.0f);
          Cb[(size_t)row * HH + col] = f2bf(v);
          Cf[(size_t)row * HH + col] = v;
        } else {
          Cb[(size_t)row * HH + col] = f2bf(v);
        }
      }
}

// ---------------------------------------------------------------------------
__global__ __launch_bounds__(256) void fused_kernel(KParams p) {
  cg::grid_group grid = cg::this_grid();
  __shared__ uint4 smem[4096];  // 64 KiB, phase-shared
  const int bid = blockIdx.x;
  const int t = threadIdx.x;
  const int lane = t & 63;
  const int wid = t >> 6;

  // ===== Phase 0: prep (mask sniff / bf16 converts / ELL build) =====
  for (int vb = bid; vb < PB_TOT; vb += NBLK) {
    if (vb == 0) {
      // mask dtype sniff over first 65536 bytes, one block, LDS-reduced.
      int* df = (int*)smem;
      if (t < 2) df[t] = 0;
      __syncthreads();
      int nonz = 0, isf = 0;
      const uint4* mask4 = (const uint4*)p.mask;
      for (int i = t; i < 4096; i += 256) {
        const uint4 v = mask4[i];
        const unsigned all = v.x | v.y | v.z | v.w;
        if (all & 0xFFFFFF00u) nonz = 1;
        if (((v.x >> 24) == 0x3fu) || ((v.y >> 24) == 0x3fu) ||
            ((v.z >> 24) == 0x3fu) || ((v.w >> 24) == 0x3fu))
          isf = 1;
      }
      if (nonz) atomicOr(&df[0], 1);
      if (isf) atomicOr(&df[1], 1);
      __syncthreads();
      if (t == 0) p.flags[0] = df[1] ? 2 : (df[0] ? 0 : 1);
      __syncthreads();  // df dead before any smem reuse
    } else if (vb < PB_XS) {
      const int i = (vb - PB_DET) * 256 + t;  // 0..262143 float4
      const float4 v = ((const float4*)p.xs)[i];
      ushort4 o;
      o.x = f2bf(v.x); o.y = f2bf(v.y); o.z = f2bf(v.z); o.w = f2bf(v.w);
      ((ushort4*)p.xsb)[i] = o;
    } else if (vb < PB_W) {
      const int idx = (vb - PB_XS) * 256 + t;
      if (idx < FF * HH) {  // WinT[n][k] = W_in[k][n]
        const int n = idx >> 7, k = idx & (FF - 1);
        p.WinT[idx] = f2bf(p.W_in[k * HH + n]);
      } else {
        const int j = idx - FF * HH;
        const int l = j >> 16, n = (j >> 8) & 255, k = j & 255;
        p.WsT[j] = f2bf(p.Ws[((size_t)l * HH + k) * HH + n]);
      }
    } else {
      const int r = (vb - PB_W) * 4 + wid;  // 0..8191
      const float* __restrict__ Arow = p.Adj + (size_t)r * NN;
      int cnt = 0;
      for (int mc = 0; mc < NN; mc += 64) {
        const float a = Arow[mc + lane];
        const unsigned long long bal = __ballot(a != 0.0f);
        if (a != 0.0f) {
          const int pos = cnt + __popcll(bal & ((1ULL << lane) - 1ULL));
          if (pos < ELLCAP) {
            uint2 e;
            e.x = __float_as_uint(a);
            e.y = (unsigned)(mc + lane);
            p.ell[(size_t)r * ELLCAP + pos] = e;
          }
        }
        cnt += __popcll(bal);
      }
      if (lane == 0) p.cntArr[r] = min(cnt, ELLCAP);
    }
  }
  grid.sync();

  // ===== Phase 1: input GEMM (K=128): X0,Xb = relu(xsb @ WinT^T + b_in) ====
  for (int vt = bid; vt < 512; vt += NBLK)
    gemm_tile<FF, true>(p.xsb, p.WinT, p.b_in, p.Xb, p.X0, smem, vt, t);
  grid.sync();

  // ===== Phases 2..9: L layers of (GEMM K=256 ; ELL SpMM) =====
  for (int i = 0; i < LL; ++i) {
    for (int vt = bid; vt < 512; vt += NBLK)
      gemm_tile<HH, false>(p.Xb, p.WsT + (size_t)i * HH * HH, nullptr, p.Yb,
                           nullptr, smem, vt, t);
    grid.sync();
    // SpMM (R5-validated body): one wave per row, lane owns 4 cols,
    // 2-way unrolled gather loop. 2048 virtual blocks of 4 rows.
    {
      const int fin = (i == LL - 1);
      const float* __restrict__ bias = p.bs + (size_t)i * HH;
      for (int vt = bid; vt < 2048; vt += NBLK) {
        const int r = vt * 4 + wid;  // 0..8191
        const int g = r >> 10;
        const unsigned short* __restrict__ Yg = p.Yb + (size_t)g * NN * HH;
        const int cnt = p.cntArr[r];
        const uint2* __restrict__ erow = p.ell + (size_t)r * ELLCAP;
        float p0 = 0.f, p1 = 0.f, p2 = 0.f, p3 = 0.f;
        float q0 = 0.f, q1 = 0.f, q2 = 0.f, q3 = 0.f;
        for (int base = 0; base < cnt; base += 64) {
          const int m = min(64, cnt - base);
          const uint2 e = erow[base + ((lane < m) ? lane : 0)];
          int j = 0;
          for (; j + 2 <= m; j += 2) {
            const float v0 = __uint_as_float(__shfl(e.x, j));
            const int i0 = (int)__shfl(e.y, j);
            const float v1 = __uint_as_float(__shfl(e.x, j + 1));
            const int i1 = (int)__shfl(e.y, j + 1);
            const ushort4 y0 =
                *(const ushort4*)(Yg + (size_t)i0 * HH + (lane << 2));
            const ushort4 y1 =
                *(const ushort4*)(Yg + (size_t)i1 * HH + (lane << 2));
            p0 += v0 * bf2f(y0.x); p1 += v0 * bf2f(y0.y);
            p2 += v0 * bf2f(y0.z); p3 += v0 * bf2f(y0.w);
            q0 += v1 * bf2f(y1.x); q1 += v1 * bf2f(y1.y);
            q2 += v1 * bf2f(y1.z); q3 += v1 * bf2f(y1.w);
          }
          if (j < m) {
            const float v0 = __uint_as_float(__shfl(e.x, j));
            const int i0 = (int)__shfl(e.y, j);
            const ushort4 y0 =
                *(const ushort4*)(Yg + (size_t)i0 * HH + (lane << 2));
            p0 += v0 * bf2f(y0.x); p1 += v0 * bf2f(y0.y);
            p2 += v0 * bf2f(y0.z); p3 += v0 * bf2f(y0.w);
          }
        }
        const float4 b4 = *(const float4*)(bias + (lane << 2));
        const float h0 = p0 + q0 + b4.x, h1 = p1 + q1 + b4.y;
        const float h2 = p2 + q2 + b4.z, h3 = p3 + q3 + b4.w;
        const size_t rowoff = (size_t)r * HH;
        if (!fin) {
          ushort4 o;
          o.x = f2bf(fmaxf(h0, 0.f));
          o.y = f2bf(fmaxf(h1, 0.f));
          o.z = f2bf(fmaxf(h2, 0.f));
          o.w = f2bf(fmaxf(h3, 0.f));
          *(ushort4*)(p.Xb + rowoff + (lane << 2)) = o;
        } else {
          float mx = fmaxf(fmaxf(h0, h1), fmaxf(h2, h3));
#pragma unroll
          for (int off = 32; off >= 1; off >>= 1)
            mx = fmaxf(mx, __shfl_xor(mx, off));
          const float e0 = __expf(h0 - mx), e1 = __expf(h1 - mx);
          const float e2 = __expf(h2 - mx), e3 = __expf(h3 - mx);
          float s = e0 + e1 + e2 + e3;
#pragma unroll
          for (int off = 32; off >= 1; off >>= 1) s += __shfl_xor(s, off);
          const float inv = 1.0f / s;
          const float4 x0 = *(const float4*)(p.X0 + rowoff + (lane << 2));
          float4 o;
          o.x = e0 * inv + x0.x;
          o.y = e1 * inv + x0.y;
          o.z = e2 * inv + x0.z;
          o.w = e3 * inv + x0.w;
          *(float4*)(p.X + rowoff + (lane << 2)) = o;
        }
      }
    }
    grid.sync();
  }

  // ===== Phase 10: masked-mean partials (1024 vbs over 256 blocks) =====
  {
    unsigned char* m = (unsigned char*)smem;
    const int mode = p.flags[0];
    for (int vb = bid; vb < 16 * BB; vb += NBLK) {
      const int c = vb & 15, b = vb >> 4;
      const int n0 = c * 64;
      __syncthreads();  // protect smem m reuse across vb iterations
      if (t < 64) {
        const int n = n0 + t;
        bool on;
        if (mode == 1) on = ((const int*)p.mask)[(size_t)b * NN + n] != 0;
        else if (mode == 2) on = ((const float*)p.mask)[(size_t)b * NN + n] != 0.0f;
        else on = ((const unsigned char*)p.mask)[(size_t)b * NN + n] != 0;
        m[t] = on ? 1 : 0;
      }
      __syncthreads();
      const int g = p.graph[b];
      const float* __restrict__ Xg = p.X + ((size_t)g * NN + n0) * HH;
      float a0 = 0.f, a1 = 0.f, a2 = 0.f, a3 = 0.f;
      int c0 = 0, c1 = 0, c2 = 0, c3 = 0;
#pragma unroll 4
      for (int n = 0; n < 16; ++n) {
        if (m[n])      { a0 += Xg[(size_t)n * HH + t]; c0++; }
        if (m[n + 16]) { a1 += Xg[(size_t)(n + 16) * HH + t]; c1++; }
        if (m[n + 32]) { a2 += Xg[(size_t)(n + 32) * HH + t]; c2++; }
        if (m[n + 48]) { a3 += Xg[(size_t)(n + 48) * HH + t]; c3++; }
      }
      p.partial[((size_t)b * 16 + c) * HH + t] = (a0 + a1) + (a2 + a3);
      if (t == 0) p.cntbuf[b * 16 + c] = (float)((c0 + c1) + (c2 + c3));
    }
  }
  grid.sync();

  // ===== Phase 11: final reduce (blocks 0..63) =====
  if (bid < BB) {
    const int b = bid;
    float s = 0.f;
#pragma unroll
    for (int c = 0; c < 16; ++c) s += p.partial[((size_t)b * 16 + c) * HH + t];
    float cnt = 0.f;
#pragma unroll
    for (int c = 0; c < 16; ++c) cnt += p.cntbuf[b * 16 + c];
    p.out[(size_t)b * HH + t] = s / fmaxf(cnt, 1.0f);
  }
}

// ---------------------------------------------------------------------------
extern "C" void kernel_launch(void* const* d_in, const int* in_sizes, int n_in,
                              void* d_out, int out_size, void* d_ws,
                              size_t ws_size, hipStream_t stream) {
  KParams p;
  p.graph = (const int*)d_in[0];
  p.mask = d_in[1];
  p.xs = (const float*)d_in[2];
  p.Adj = (const float*)d_in[3];
  p.W_in = (const float*)d_in[4];
  p.b_in = (const float*)d_in[5];
  p.Ws = (const float*)d_in[6];
  p.bs = (const float*)d_in[7];
  p.out = (float*)d_out;

  // Workspace: X(8M) | X0(8M) | Yb(4M) | Xb(4M) | xsb(2M) | WinT(64K)
  //          | WsT(512K) | ell(6M) | cnt(32K) | flags | partial(1M) | cntbuf
  p.X = (float*)d_ws;
  p.X0 = p.X + (size_t)MM * HH;
  p.Yb = (unsigned short*)(p.X0 + (size_t)MM * HH);
  p.Xb = p.Yb + (size_t)MM * HH;
  p.xsb = p.Xb + (size_t)MM * HH;
  p.WinT = p.xsb + (size_t)MM * FF;
  p.WsT = p.WinT + (size_t)HH * FF;
  p.ell = (uint2*)(p.WsT + (size_t)LL * HH * HH);
  p.cntArr = (int*)(p.ell + (size_t)MM * ELLCAP);
  p.flags = p.cntArr + MM;
  p.partial = (float*)(p.flags + 2);
  p.cntbuf = p.partial + (size_t)BB * 16 * HH;

  void* args[] = {&p};
  hipLaunchCooperativeKernel((void*)fused_kernel, dim3(NBLK), dim3(256), args,
                             0, stream);
}

// Round 9
// 222.644 us; speedup vs baseline: 3.1062x; 3.1062x over previous
//
#include <hip/hip_runtime.h>
#include <hip/hip_bf16.h>

// Problem constants: G=8 graphs, N=1024 nodes, F=128 in-feat, H=256 hidden,
// L=4 layers, B=64 samples.
#define GG 8
#define NN 1024
#define FF 128
#define HH 256
#define LL 4
#define BB 64
#define MM (GG * NN)  // 8192 fused (g,n) rows
#define ELLCAP 96     // max nnz/row stored (binomial(1024,.02) max ~48)

typedef __attribute__((ext_vector_type(8))) short bf16x8_t;  // 8 bf16 = 4 VGPR
typedef __attribute__((ext_vector_type(4))) float f32x4_t;   // MFMA acc

__device__ inline unsigned short f2bf(float f) {
  union { float f; unsigned u; } c;
  c.f = f;
  unsigned r = (c.u + 0x7fffu + ((c.u >> 16) & 1u)) >> 16;  // RNE
  return (unsigned short)r;
}
__device__ inline float bf2f(unsigned short u) {
  union { unsigned u; float f; } c;
  c.u = (unsigned)u << 16;
  return c.f;
}

// ---------------------------------------------------------------------------
// Fused preprocessing. blockIdx partitions 4 independent jobs:
//   0            : mask dtype sniff (single block, direct write -> no memset)
//   [1,1025)     : xs f32 -> bf16 (262144 float4)
//   [1025,2177)  : W_in/Ws -> bf16 transposed
//   [2177,4225)  : ELL build, one wave per adjacency row
__global__ __launch_bounds__(256) void prep_kernel(
    const uint4* __restrict__ mask4, int* __restrict__ flags,
    const float4* __restrict__ xs4, ushort4* __restrict__ xsb4,
    const float* __restrict__ W_in, const float* __restrict__ Ws,
    unsigned short* __restrict__ WinT, unsigned short* __restrict__ WsT,
    const float* __restrict__ Adj, uint2* __restrict__ ell,
    int* __restrict__ cntArr) {
  const int bx = blockIdx.x;
  const int t = threadIdx.x;
  if (bx == 0) {
    // mode: 0 = 1-byte bool, 1 = int32 (0/1), 2 = float32
    __shared__ int df[2];
    if (t < 2) df[t] = 0;
    __syncthreads();
    int nonz = 0, isf = 0;
    for (int i = t; i < 4096; i += 256) {  // first 65536 bytes
      const uint4 v = mask4[i];
      const unsigned all = v.x | v.y | v.z | v.w;
      if (all & 0xFFFFFF00u) nonz = 1;
      if (((v.x >> 24) == 0x3fu) || ((v.y >> 24) == 0x3fu) ||
          ((v.z >> 24) == 0x3fu) || ((v.w >> 24) == 0x3fu))
        isf = 1;
    }
    if (nonz) atomicOr(&df[0], 1);
    if (isf) atomicOr(&df[1], 1);
    __syncthreads();
    if (t == 0) flags[0] = df[1] ? 2 : (df[0] ? 0 : 1);
  } else if (bx < 1025) {
    const int i = (bx - 1) * 256 + t;
    const float4 v = xs4[i];
    ushort4 o;
    o.x = f2bf(v.x); o.y = f2bf(v.y); o.z = f2bf(v.z); o.w = f2bf(v.w);
    xsb4[i] = o;
  } else if (bx < 2177) {
    const int idx = (bx - 1025) * 256 + t;
    if (idx < FF * HH) {  // WinT[n][k] = W_in[k][n]
      const int n = idx >> 7, k = idx & (FF - 1);
      WinT[idx] = f2bf(W_in[k * HH + n]);
    } else {
      const int j = idx - FF * HH;
      const int l = j >> 16, n = (j >> 8) & 255, k = j & 255;
      WsT[j] = f2bf(Ws[((size_t)l * HH + k) * HH + n]);
    }
  } else {
    const int lane = t & 63;
    const int wid = t >> 6;
    const int r = (bx - 2177) * 4 + wid;  // 0..8191
    const float* __restrict__ Arow = Adj + (size_t)r * NN;
    int cnt = 0;
    for (int mc = 0; mc < NN; mc += 64) {
      const float a = Arow[mc + lane];
      const unsigned long long bal = __ballot(a != 0.0f);
      if (a != 0.0f) {
        const int pos = cnt + __popcll(bal & ((1ULL << lane) - 1ULL));
        if (pos < ELLCAP) {
          uint2 e;
          e.x = __float_as_uint(a);
          e.y = (unsigned)(mc + lane);
          ell[(size_t)r * ELLCAP + pos] = e;
        }
      }
      cnt += __popcll(bal);
    }
    if (lane == 0) cntArr[r] = min(cnt, ELLCAP);
  }
}

// ---------------------------------------------------------------------------
// Input GEMM (R5-validated): C = A[M][128] @ WinT[HH][128]^T, one-shot-K LDS,
// XOR swizzle, 64x64 tile, 4 waves, fused bias+relu, writes bf16 Cb + f32 Cf.
__global__ __launch_bounds__(256) void input_gemm_kernel(
    const unsigned short* __restrict__ A, const unsigned short* __restrict__ BT,
    const float* __restrict__ bias, unsigned short* __restrict__ Cb,
    float* __restrict__ Cf) {
  constexpr int K = FF, KS = K / 8;
  __shared__ uint4 As4[64 * KS];
  __shared__ uint4 Bs4[64 * KS];
  const int t = threadIdx.x;
  const int lane = t & 63;
  const int w = t >> 6;
  const int wm = (w >> 1) * 32;
  const int wn = (w & 1) * 32;
  const int m0 = blockIdx.x * 64;
  const int n0 = blockIdx.y * 64;
  const int lk = lane >> 4;
  const int lr = lane & 15;
  const uint4* __restrict__ Ag = (const uint4*)(A + (size_t)m0 * K);
  const uint4* __restrict__ Bg = (const uint4*)(BT + (size_t)n0 * K);
#pragma unroll
  for (int it = 0; it < K / 32; ++it) {
    const int c = it * 256 + t;
    const int row = c / KS;
    const int k = c % KS;
    const int slot = row * KS + (k ^ (row & 7));
    As4[slot] = Ag[c];
    Bs4[slot] = Bg[c];
  }
  __syncthreads();
  f32x4_t acc[2][2] = {};
#pragma unroll
  for (int ks = 0; ks < K / 32; ++ks) {
    const int q = ks * 4 + lk;
    const int ra0 = wm + lr, ra1 = wm + 16 + lr;
    const int rb0 = wn + lr, rb1 = wn + 16 + lr;
    const bf16x8_t a0 = *(const bf16x8_t*)(&As4[ra0 * KS + (q ^ (ra0 & 7))]);
    const bf16x8_t a1 = *(const bf16x8_t*)(&As4[ra1 * KS + (q ^ (ra1 & 7))]);
    const bf16x8_t b0 = *(const bf16x8_t*)(&Bs4[rb0 * KS + (q ^ (rb0 & 7))]);
    const bf16x8_t b1 = *(const bf16x8_t*)(&Bs4[rb1 * KS + (q ^ (rb1 & 7))]);
    acc[0][0] = __builtin_amdgcn_mfma_f32_16x16x32_bf16(a0, b0, acc[0][0], 0, 0, 0);
    acc[0][1] = __builtin_amdgcn_mfma_f32_16x16x32_bf16(a0, b1, acc[0][1], 0, 0, 0);
    acc[1][0] = __builtin_amdgcn_mfma_f32_16x16x32_bf16(a1, b0, acc[1][0], 0, 0, 0);
    acc[1][1] = __builtin_amdgcn_mfma_f32_16x16x32_bf16(a1, b1, acc[1][1], 0, 0, 0);
  }
#pragma unroll
  for (int rg = 0; rg < 2; ++rg)
#pragma unroll
    for (int cg = 0; cg < 2; ++cg)
#pragma unroll
      for (int j = 0; j < 4; ++j) {
        // verified C/D layout: col = lane&15, row = (lane>>4)*4 + reg
        const int row = m0 + wm + rg * 16 + (lane >> 4) * 4 + j;
        const int col = n0 + wn + cg * 16 + lr;
        float v = acc[rg][cg][j] + bias[col];
        v = fmaxf(v, 0.0f);
        Cb[(size_t)row * HH + col] = f2bf(v);
        Cf[(size_t)row * HH + col] = v;
      }
}

// ---------------------------------------------------------------------------
// FUSED LAYER: X_next = act((A @ X) @ W + b) using associativity.
// Block = 16 rows, 256 threads (4 waves). Phase A: ELL SpMM -> Z[16][256] bf16
// in LDS (padded rows, 2-way-max bank aliasing = free). Phase B: Z @ W via
// MFMA, W staged per-64-K-chunk with XOR swizzle. FINAL: writes f32 H (pre-
// softmax); else bias+relu -> bf16.
template <bool FINAL>
__global__ __launch_bounds__(256) void layer_kernel(
    const uint2* __restrict__ ell, const int* __restrict__ cntArr,
    const unsigned short* __restrict__ Xin, const unsigned short* __restrict__ WT,
    const float* __restrict__ bias, unsigned short* __restrict__ Xout,
    float* __restrict__ Hout) {
  __shared__ __align__(16) unsigned short Z[16][264];  // 256 + 8 pad
  __shared__ uint4 Wl[256 * 8];                        // 32KB k-chunk
  const int t = threadIdx.x;
  const int lane = t & 63;
  const int w = t >> 6;
  const int r0 = blockIdx.x * 16;
  const int g = r0 >> 10;  // 16 divides 1024 -> whole block same graph
  const unsigned short* __restrict__ Xg = Xin + (size_t)g * NN * HH;

  // ----- Phase A: Z rows w*4 .. w*4+3 (R5-validated gather body, no bias) ---
  for (int rr = w * 4; rr < w * 4 + 4; ++rr) {
    const int r = r0 + rr;
    const int cnt = cntArr[r];
    const uint2* __restrict__ erow = ell + (size_t)r * ELLCAP;
    float p0 = 0.f, p1 = 0.f, p2 = 0.f, p3 = 0.f;
    float q0 = 0.f, q1 = 0.f, q2 = 0.f, q3 = 0.f;
    for (int base = 0; base < cnt; base += 64) {
      const int m = min(64, cnt - base);
      const uint2 e = erow[base + ((lane < m) ? lane : 0)];
      int j = 0;
      for (; j + 2 <= m; j += 2) {
        const float v0 = __uint_as_float(__shfl(e.x, j));
        const int i0 = (int)__shfl(e.y, j);
        const float v1 = __uint_as_float(__shfl(e.x, j + 1));
        const int i1 = (int)__shfl(e.y, j + 1);
        const ushort4 y0 = *(const ushort4*)(Xg + (size_t)i0 * HH + (lane << 2));
        const ushort4 y1 = *(const ushort4*)(Xg + (size_t)i1 * HH + (lane << 2));
        p0 += v0 * bf2f(y0.x); p1 += v0 * bf2f(y0.y);
        p2 += v0 * bf2f(y0.z); p3 += v0 * bf2f(y0.w);
        q0 += v1 * bf2f(y1.x); q1 += v1 * bf2f(y1.y);
        q2 += v1 * bf2f(y1.z); q3 += v1 * bf2f(y1.w);
      }
      if (j < m) {
        const float v0 = __uint_as_float(__shfl(e.x, j));
        const int i0 = (int)__shfl(e.y, j);
        const ushort4 y0 = *(const ushort4*)(Xg + (size_t)i0 * HH + (lane << 2));
        p0 += v0 * bf2f(y0.x); p1 += v0 * bf2f(y0.y);
        p2 += v0 * bf2f(y0.z); p3 += v0 * bf2f(y0.w);
      }
    }
    ushort4 z;
    z.x = f2bf(p0 + q0); z.y = f2bf(p1 + q1);
    z.z = f2bf(p2 + q2); z.w = f2bf(p3 + q3);
    *(ushort4*)&Z[rr][lane << 2] = z;
  }
  __syncthreads();

  // ----- Phase B: out[16][256] = Z @ W; wave w owns cols [w*64, w*64+64) ----
  const int lr = lane & 15;
  const int lk = lane >> 4;
  f32x4_t acc[4] = {};
  for (int kc = 0; kc < 4; ++kc) {  // K chunks of 64
    if (kc) __syncthreads();        // protect Wl reuse
#pragma unroll
    for (int it = 0; it < 8; ++it) {  // stage WT[0..255][kc*64 .. +64]
      const int c = it * 256 + t;
      const int n = c >> 3, k8 = c & 7;
      Wl[n * 8 + (k8 ^ (n & 7))] = ((const uint4*)WT)[n * 32 + kc * 8 + k8];
    }
    __syncthreads();
#pragma unroll
    for (int ks = 0; ks < 2; ++ks) {
      const bf16x8_t a = *(const bf16x8_t*)&Z[lr][kc * 64 + ks * 32 + lk * 8];
      const int k8 = ks * 4 + lk;
#pragma unroll
      for (int nt = 0; nt < 4; ++nt) {
        const int n = w * 64 + nt * 16 + lr;
        const bf16x8_t b = *(const bf16x8_t*)&Wl[n * 8 + (k8 ^ (n & 7))];
        acc[nt] = __builtin_amdgcn_mfma_f32_16x16x32_bf16(a, b, acc[nt], 0, 0, 0);
      }
    }
  }
  // ----- Epilogue: verified C/D layout col=lane&15, row=(lane>>4)*4+reg -----
#pragma unroll
  for (int nt = 0; nt < 4; ++nt)
#pragma unroll
    for (int j = 0; j < 4; ++j) {
      const int row = r0 + lk * 4 + j;
      const int col = w * 64 + nt * 16 + lr;
      const float v = acc[nt][j] + bias[col];
      if (FINAL)
        Hout[(size_t)row * HH + col] = v;
      else
        Xout[(size_t)row * HH + col] = f2bf(fmaxf(v, 0.0f));
    }
}

// ---------------------------------------------------------------------------
// Softmax over 256 cols + residual (R5-validated epilogue, H from global).
// One wave per row, lane owns cols lane*4..+3. In-place-safe (read-then-write).
__global__ __launch_bounds__(256) void softmax_res_kernel(
    const float* __restrict__ H, const float* __restrict__ X0,
    float* __restrict__ X) {
  const int lane = threadIdx.x & 63;
  const int wid = threadIdx.x >> 6;
  const int r = blockIdx.x * 4 + wid;
  const size_t rowoff = (size_t)r * HH;
  const float4 h4 = *(const float4*)(H + rowoff + (lane << 2));
  const float h0 = h4.x, h1 = h4.y, h2 = h4.z, h3 = h4.w;
  float mx = fmaxf(fmaxf(h0, h1), fmaxf(h2, h3));
#pragma unroll
  for (int off = 32; off >= 1; off >>= 1) mx = fmaxf(mx, __shfl_xor(mx, off));
  const float e0 = __expf(h0 - mx), e1 = __expf(h1 - mx);
  const float e2 = __expf(h2 - mx), e3 = __expf(h3 - mx);
  float s = e0 + e1 + e2 + e3;
#pragma unroll
  for (int off = 32; off >= 1; off >>= 1) s += __shfl_xor(s, off);
  const float inv = 1.0f / s;
  const float4 x0 = *(const float4*)(X0 + rowoff + (lane << 2));
  float4 o;
  o.x = e0 * inv + x0.x;
  o.y = e1 * inv + x0.y;
  o.z = e2 * inv + x0.z;
  o.w = e3 * inv + x0.w;
  *(float4*)(X + rowoff + (lane << 2)) = o;
}

// ---------------------------------------------------------------------------
// Masked mean, stage 1 (R5-validated): grid (16 chunks x 64 samples).
__global__ __launch_bounds__(256) void mm_partial_kernel(
    const float* __restrict__ X, const int* __restrict__ graph,
    const void* __restrict__ mask, const int* __restrict__ flags,
    float* __restrict__ partial, float* __restrict__ cntbuf) {
  __shared__ unsigned char m[64];
  const int c = blockIdx.x;
  const int b = blockIdx.y;
  const int h = threadIdx.x;
  const int n0 = c * 64;
  const int mode = flags[0];
  if (h < 64) {
    const int n = n0 + h;
    bool on;
    if (mode == 1) on = ((const int*)mask)[(size_t)b * NN + n] != 0;
    else if (mode == 2) on = ((const float*)mask)[(size_t)b * NN + n] != 0.0f;
    else on = ((const unsigned char*)mask)[(size_t)b * NN + n] != 0;
    m[h] = on ? 1 : 0;
  }
  __syncthreads();
  const int g = graph[b];
  const float* __restrict__ Xg = X + ((size_t)g * NN + n0) * HH;
  float a0 = 0.f, a1 = 0.f, a2 = 0.f, a3 = 0.f;
  int c0 = 0, c1 = 0, c2 = 0, c3 = 0;
#pragma unroll 4
  for (int n = 0; n < 16; ++n) {
    if (m[n])      { a0 += Xg[(size_t)n * HH + h]; c0++; }
    if (m[n + 16]) { a1 += Xg[(size_t)(n + 16) * HH + h]; c1++; }
    if (m[n + 32]) { a2 += Xg[(size_t)(n + 32) * HH + h]; c2++; }
    if (m[n + 48]) { a3 += Xg[(size_t)(n + 48) * HH + h]; c3++; }
  }
  partial[((size_t)b * 16 + c) * HH + h] = (a0 + a1) + (a2 + a3);
  if (h == 0) cntbuf[b * 16 + c] = (float)((c0 + c1) + (c2 + c3));
}

__global__ __launch_bounds__(256) void mm_reduce_kernel(
    const float* __restrict__ partial, const float* __restrict__ cntbuf,
    float* __restrict__ out) {
  const int b = blockIdx.x, h = threadIdx.x;
  float s = 0.f;
#pragma unroll
  for (int c = 0; c < 16; ++c) s += partial[((size_t)b * 16 + c) * HH + h];
  float cnt = 0.f;
#pragma unroll
  for (int c = 0; c < 16; ++c) cnt += cntbuf[b * 16 + c];
  out[(size_t)b * HH + h] = s / fmaxf(cnt, 1.0f);
}

// ---------------------------------------------------------------------------
extern "C" void kernel_launch(void* const* d_in, const int* in_sizes, int n_in,
                              void* d_out, int out_size, void* d_ws,
                              size_t ws_size, hipStream_t stream) {
  const int* graph = (const int*)d_in[0];
  const void* mask = d_in[1];
  const float* xs = (const float*)d_in[2];    // [G][N][F] f32
  const float* As = (const float*)d_in[3];    // [G][N][N] f32
  const float* W_in = (const float*)d_in[4];  // [F][H] f32
  const float* b_in = (const float*)d_in[5];  // [H]
  const float* Ws = (const float*)d_in[6];    // [L][H][H] f32
  const float* bs = (const float*)d_in[7];    // [L][H]
  float* out = (float*)d_out;

  // Workspace: X(8M) | X0(8M) | Yb(4M) | Xb(4M) | xsb(2M) | WinT(64K)
  //          | WsT(512K) | ell(6M) | cnt(32K) | flags | partial(1M) | cntbuf
  float* X = (float*)d_ws;
  float* X0 = X + (size_t)MM * HH;
  unsigned short* Yb = (unsigned short*)(X0 + (size_t)MM * HH);
  unsigned short* Xb = Yb + (size_t)MM * HH;
  unsigned short* xsb = Xb + (size_t)MM * HH;
  unsigned short* WinT = xsb + (size_t)MM * FF;
  unsigned short* WsT = WinT + (size_t)HH * FF;
  uint2* ell = (uint2*)(WsT + (size_t)LL * HH * HH);
  int* cntArr = (int*)(ell + (size_t)MM * ELLCAP);
  int* flags = cntArr + MM;
  float* partial = (float*)(flags + 2);
  float* cntbuf = partial + (size_t)BB * 16 * HH;

  // 1) prep: detect + converts + ELL (4225 blocks)
  prep_kernel<<<4225, 256, 0, stream>>>((const uint4*)mask, flags,
                                        (const float4*)xs, (ushort4*)xsb, W_in,
                                        Ws, WinT, WsT, As, ell, cntArr);
  // 2) input GEMM: Xb (bf16), X0 (f32) = relu(xs @ W_in + b_in)
  input_gemm_kernel<<<dim3(MM / 64, HH / 64), 256, 0, stream>>>(xsb, WinT, b_in,
                                                                Xb, X0);
  // 3-6) fused layers via (A@X)@W associativity, ping-pong Xb <-> Yb
  layer_kernel<false><<<MM / 16, 256, 0, stream>>>(ell, cntArr, Xb, WsT, bs, Yb,
                                                   nullptr);
  layer_kernel<false><<<MM / 16, 256, 0, stream>>>(
      ell, cntArr, Yb, WsT + (size_t)HH * HH, bs + HH, Xb, nullptr);
  layer_kernel<false><<<MM / 16, 256, 0, stream>>>(
      ell, cntArr, Xb, WsT + (size_t)2 * HH * HH, bs + 2 * HH, Yb, nullptr);
  layer_kernel<true><<<MM / 16, 256, 0, stream>>>(
      ell, cntArr, Yb, WsT + (size_t)3 * HH * HH, bs + 3 * HH, nullptr, X);
  // 7) softmax + residual (in-place on X)
  softmax_res_kernel<<<MM / 4, 256, 0, stream>>>(X, X0, X);
  // 8-9) masked mean
  mm_partial_kernel<<<dim3(16, BB), 256, 0, stream>>>(X, graph, mask, flags,
                                                      partial, cntbuf);
  mm_reduce_kernel<<<BB, 256, 0, stream>>>(partial, cntbuf, out);
}

// Round 10
// 211.372 us; speedup vs baseline: 3.2719x; 1.0533x over previous
//
#include <hip/hip_runtime.h>
#include <hip/hip_bf16.h>

// Problem constants: G=8 graphs, N=1024 nodes, F=128 in-feat, H=256 hidden,
// L=4 layers, B=64 samples.
#define GG 8
#define NN 1024
#define FF 128
#define HH 256
#define LL 4
#define BB 64
#define MM (GG * NN)  // 8192 fused (g,n) rows
#define ELLCAP 96     // max nnz/row stored (binomial(1024,.02) max ~48)
#define NC 32         // masked-mean chunks (32 nodes each)

typedef __attribute__((ext_vector_type(8))) short bf16x8_t;  // 8 bf16 = 4 VGPR
typedef __attribute__((ext_vector_type(4))) float f32x4_t;   // MFMA acc

__device__ inline unsigned short f2bf(float f) {
  union { float f; unsigned u; } c;
  c.f = f;
  unsigned r = (c.u + 0x7fffu + ((c.u >> 16) & 1u)) >> 16;  // RNE
  return (unsigned short)r;
}
__device__ inline float bf2f(unsigned short u) {
  union { unsigned u; float f; } c;
  c.u = (unsigned)u << 16;
  return c.f;
}

// ---------------------------------------------------------------------------
// prep: bx==0 mask-dtype sniff (direct flag write); [1,1025) xs f32->bf16;
// [1025,1097) coalesced 64x64-tile transposes of W_in (8 tiles) and Ws (64).
__global__ __launch_bounds__(256) void prep_kernel(
    const uint4* __restrict__ mask4, int* __restrict__ flags,
    const float4* __restrict__ xs4, ushort4* __restrict__ xsb4,
    const float* __restrict__ W_in, const float* __restrict__ Ws,
    unsigned short* __restrict__ WinT, unsigned short* __restrict__ WsT) {
  __shared__ float Ld[64][65];
  __shared__ int df[2];
  const int bx = blockIdx.x;
  const int t = threadIdx.x;
  if (bx == 0) {
    // mode: 0 = 1-byte bool, 1 = int32 (0/1), 2 = float32
    if (t < 2) df[t] = 0;
    __syncthreads();
    int nonz = 0, isf = 0;
    for (int i = t; i < 4096; i += 256) {  // first 65536 bytes
      const uint4 v = mask4[i];
      const unsigned all = v.x | v.y | v.z | v.w;
      if (all & 0xFFFFFF00u) nonz = 1;
      if (((v.x >> 24) == 0x3fu) || ((v.y >> 24) == 0x3fu) ||
          ((v.z >> 24) == 0x3fu) || ((v.w >> 24) == 0x3fu))
        isf = 1;
    }
    if (nonz) atomicOr(&df[0], 1);
    if (isf) atomicOr(&df[1], 1);
    __syncthreads();
    if (t == 0) flags[0] = df[1] ? 2 : (df[0] ? 0 : 1);
  } else if (bx < 1025) {
    const int i = (bx - 1) * 256 + t;
    const float4 v = xs4[i];
    ushort4 o;
    o.x = f2bf(v.x); o.y = f2bf(v.y); o.z = f2bf(v.z); o.w = f2bf(v.w);
    xsb4[i] = o;
  } else {
    int tt = bx - 1025;
    const float* src;
    unsigned short* dst;
    int R, C, r0, c0;
    if (tt < 8) {  // W_in [128][256] -> WinT [256][128]
      src = W_in; dst = WinT; R = FF; C = HH;
      r0 = (tt >> 2) * 64; c0 = (tt & 3) * 64;
    } else {       // Ws[l] [256][256] -> WsT[l] [256][256]
      tt -= 8;
      const int l = tt >> 4, rem = tt & 15;
      src = Ws + (size_t)l * HH * HH;
      dst = WsT + (size_t)l * HH * HH;
      R = HH; C = HH;
      r0 = (rem >> 2) * 64; c0 = (rem & 3) * 64;
    }
#pragma unroll
    for (int i = 0; i < 16; ++i) {  // coalesced read
      const int idx = i * 256 + t;
      const int r = idx >> 6, c = idx & 63;
      Ld[r][c] = src[(size_t)(r0 + r) * C + c0 + c];
    }
    __syncthreads();
#pragma unroll
    for (int i = 0; i < 16; ++i) {  // coalesced transposed write
      const int idx = i * 256 + t;
      const int cc = idx >> 6, rr = idx & 63;
      dst[(size_t)(c0 + cc) * R + r0 + rr] = f2bf(Ld[rr][cc]);
    }
  }
}

// ---------------------------------------------------------------------------
// stage2: blocks [0,512) = input GEMM (R5-validated one-shot-K body, K=128,
// fused bias+relu, writes bf16 Xb + f32 X0); blocks [512,2560) = ELL build
// (HBM-bound 32MB scan) — overlapped in one dispatch, complementary pipes.
__global__ __launch_bounds__(256) void stage2_kernel(
    const unsigned short* __restrict__ A, const unsigned short* __restrict__ BT,
    const float* __restrict__ bias, unsigned short* __restrict__ Cb,
    float* __restrict__ Cf, const float* __restrict__ Adj,
    uint2* __restrict__ ell, int* __restrict__ cntArr) {
  constexpr int K = FF, KS = K / 8;
  __shared__ uint4 As4[64 * KS];  // 16KB
  __shared__ uint4 Bs4[64 * KS];  // 16KB
  const int bx = blockIdx.x;
  const int t = threadIdx.x;
  const int lane = t & 63;
  const int w = t >> 6;
  if (bx < 512) {
    const int wm = (w >> 1) * 32;
    const int wn = (w & 1) * 32;
    const int m0 = (bx >> 2) * 64;
    const int n0 = (bx & 3) * 64;
    const int lk = lane >> 4;
    const int lr = lane & 15;
    const uint4* __restrict__ Ag = (const uint4*)(A + (size_t)m0 * K);
    const uint4* __restrict__ Bg = (const uint4*)(BT + (size_t)n0 * K);
#pragma unroll
    for (int it = 0; it < K / 32; ++it) {
      const int c = it * 256 + t;
      const int row = c / KS;
      const int k = c % KS;
      const int slot = row * KS + (k ^ (row & 7));
      As4[slot] = Ag[c];
      Bs4[slot] = Bg[c];
    }
    __syncthreads();
    f32x4_t acc[2][2] = {};
#pragma unroll
    for (int ks = 0; ks < K / 32; ++ks) {
      const int q = ks * 4 + lk;
      const int ra0 = wm + lr, ra1 = wm + 16 + lr;
      const int rb0 = wn + lr, rb1 = wn + 16 + lr;
      const bf16x8_t a0 = *(const bf16x8_t*)(&As4[ra0 * KS + (q ^ (ra0 & 7))]);
      const bf16x8_t a1 = *(const bf16x8_t*)(&As4[ra1 * KS + (q ^ (ra1 & 7))]);
      const bf16x8_t b0 = *(const bf16x8_t*)(&Bs4[rb0 * KS + (q ^ (rb0 & 7))]);
      const bf16x8_t b1 = *(const bf16x8_t*)(&Bs4[rb1 * KS + (q ^ (rb1 & 7))]);
      acc[0][0] = __builtin_amdgcn_mfma_f32_16x16x32_bf16(a0, b0, acc[0][0], 0, 0, 0);
      acc[0][1] = __builtin_amdgcn_mfma_f32_16x16x32_bf16(a0, b1, acc[0][1], 0, 0, 0);
      acc[1][0] = __builtin_amdgcn_mfma_f32_16x16x32_bf16(a1, b0, acc[1][0], 0, 0, 0);
      acc[1][1] = __builtin_amdgcn_mfma_f32_16x16x32_bf16(a1, b1, acc[1][1], 0, 0, 0);
    }
#pragma unroll
    for (int rg = 0; rg < 2; ++rg)
#pragma unroll
      for (int cg = 0; cg < 2; ++cg)
#pragma unroll
        for (int j = 0; j < 4; ++j) {
          // verified C/D layout: col = lane&15, row = (lane>>4)*4 + reg
          const int row = m0 + wm + rg * 16 + (lane >> 4) * 4 + j;
          const int col = n0 + wn + cg * 16 + lr;
          float v = acc[rg][cg][j] + bias[col];
          v = fmaxf(v, 0.0f);
          Cb[(size_t)row * HH + col] = f2bf(v);
          Cf[(size_t)row * HH + col] = v;
        }
  } else {
    const int r = (bx - 512) * 4 + w;  // 0..8191
    const float* __restrict__ Arow = Adj + (size_t)r * NN;
    int cnt = 0;
    for (int mc = 0; mc < NN; mc += 64) {
      const float a = Arow[mc + lane];
      const unsigned long long bal = __ballot(a != 0.0f);
      if (a != 0.0f) {
        const int pos = cnt + __popcll(bal & ((1ULL << lane) - 1ULL));
        if (pos < ELLCAP) {
          uint2 e;
          e.x = __float_as_uint(a);
          e.y = (unsigned)(mc + lane);
          ell[(size_t)r * ELLCAP + pos] = e;
        }
      }
      cnt += __popcll(bal);
    }
    if (lane == 0) cntArr[r] = min(cnt, ELLCAP);
  }
}

// ---------------------------------------------------------------------------
// Layer GEMM (R5-validated): Yb = Xb[M][256] @ WsT[l][HH][256]^T, one-shot-K,
// XOR swizzle, 64x64 tile, 4 waves, bf16 out.
__global__ __launch_bounds__(256) void layer_gemm_kernel(
    const unsigned short* __restrict__ A, const unsigned short* __restrict__ BT,
    unsigned short* __restrict__ Cb) {
  constexpr int K = HH, KS = K / 8;
  __shared__ uint4 As4[64 * KS];  // 32KB
  __shared__ uint4 Bs4[64 * KS];  // 32KB
  const int t = threadIdx.x;
  const int lane = t & 63;
  const int w = t >> 6;
  const int wm = (w >> 1) * 32;
  const int wn = (w & 1) * 32;
  const int m0 = blockIdx.x * 64;
  const int n0 = blockIdx.y * 64;
  const int lk = lane >> 4;
  const int lr = lane & 15;
  const uint4* __restrict__ Ag = (const uint4*)(A + (size_t)m0 * K);
  const uint4* __restrict__ Bg = (const uint4*)(BT + (size_t)n0 * K);
#pragma unroll
  for (int it = 0; it < K / 32; ++it) {
    const int c = it * 256 + t;
    const int row = c / KS;
    const int k = c % KS;
    const int slot = row * KS + (k ^ (row & 7));
    As4[slot] = Ag[c];
    Bs4[slot] = Bg[c];
  }
  __syncthreads();
  f32x4_t acc[2][2] = {};
#pragma unroll
  for (int ks = 0; ks < K / 32; ++ks) {
    const int q = ks * 4 + lk;
    const int ra0 = wm + lr, ra1 = wm + 16 + lr;
    const int rb0 = wn + lr, rb1 = wn + 16 + lr;
    const bf16x8_t a0 = *(const bf16x8_t*)(&As4[ra0 * KS + (q ^ (ra0 & 7))]);
    const bf16x8_t a1 = *(const bf16x8_t*)(&As4[ra1 * KS + (q ^ (ra1 & 7))]);
    const bf16x8_t b0 = *(const bf16x8_t*)(&Bs4[rb0 * KS + (q ^ (rb0 & 7))]);
    const bf16x8_t b1 = *(const bf16x8_t*)(&Bs4[rb1 * KS + (q ^ (rb1 & 7))]);
    acc[0][0] = __builtin_amdgcn_mfma_f32_16x16x32_bf16(a0, b0, acc[0][0], 0, 0, 0);
    acc[0][1] = __builtin_amdgcn_mfma_f32_16x16x32_bf16(a0, b1, acc[0][1], 0, 0, 0);
    acc[1][0] = __builtin_amdgcn_mfma_f32_16x16x32_bf16(a1, b0, acc[1][0], 0, 0, 0);
    acc[1][1] = __builtin_amdgcn_mfma_f32_16x16x32_bf16(a1, b1, acc[1][1], 0, 0, 0);
  }
#pragma unroll
  for (int rg = 0; rg < 2; ++rg)
#pragma unroll
    for (int cg = 0; cg < 2; ++cg)
#pragma unroll
      for (int j = 0; j < 4; ++j) {
        const int row = m0 + wm + rg * 16 + (lane >> 4) * 4 + j;
        const int col = n0 + wn + cg * 16 + lr;
        Cb[(size_t)row * HH + col] = f2bf(acc[rg][cg][j]);
      }
}

// ---------------------------------------------------------------------------
// ELL SpMM (R5-validated): X = act(A @ Yb + bias). One wave per row, lane owns
// cols lane*4..+3, 2-way unrolled gather. Final: softmax + residual -> f32 X.
__global__ __launch_bounds__(256) void spmm_ell_kernel(
    const uint2* __restrict__ ell, const int* __restrict__ cntArr,
    const unsigned short* __restrict__ Yb, const float* __restrict__ bias,
    const float* __restrict__ X0, unsigned short* __restrict__ Xb,
    float* __restrict__ Xf, int final_layer) {
  const int lane = threadIdx.x & 63;
  const int wid = threadIdx.x >> 6;
  const int r = blockIdx.x * 4 + wid;  // 0..8191
  const int g = r >> 10;
  const unsigned short* __restrict__ Yg = Yb + (size_t)g * NN * HH;
  const int cnt = cntArr[r];
  const uint2* __restrict__ erow = ell + (size_t)r * ELLCAP;
  float p0 = 0.f, p1 = 0.f, p2 = 0.f, p3 = 0.f;
  float q0 = 0.f, q1 = 0.f, q2 = 0.f, q3 = 0.f;
  for (int base = 0; base < cnt; base += 64) {
    const int m = min(64, cnt - base);
    const uint2 e = erow[base + ((lane < m) ? lane : 0)];
    int j = 0;
    for (; j + 2 <= m; j += 2) {
      const float v0 = __uint_as_float(__shfl(e.x, j));
      const int i0 = (int)__shfl(e.y, j);
      const float v1 = __uint_as_float(__shfl(e.x, j + 1));
      const int i1 = (int)__shfl(e.y, j + 1);
      const ushort4 y0 = *(const ushort4*)(Yg + (size_t)i0 * HH + (lane << 2));
      const ushort4 y1 = *(const ushort4*)(Yg + (size_t)i1 * HH + (lane << 2));
      p0 += v0 * bf2f(y0.x); p1 += v0 * bf2f(y0.y);
      p2 += v0 * bf2f(y0.z); p3 += v0 * bf2f(y0.w);
      q0 += v1 * bf2f(y1.x); q1 += v1 * bf2f(y1.y);
      q2 += v1 * bf2f(y1.z); q3 += v1 * bf2f(y1.w);
    }
    if (j < m) {
      const float v0 = __uint_as_float(__shfl(e.x, j));
      const int i0 = (int)__shfl(e.y, j);
      const ushort4 y0 = *(const ushort4*)(Yg + (size_t)i0 * HH + (lane << 2));
      p0 += v0 * bf2f(y0.x); p1 += v0 * bf2f(y0.y);
      p2 += v0 * bf2f(y0.z); p3 += v0 * bf2f(y0.w);
    }
  }
  const float4 b4 = *(const float4*)(bias + (lane << 2));
  const float h0 = p0 + q0 + b4.x, h1 = p1 + q1 + b4.y;
  const float h2 = p2 + q2 + b4.z, h3 = p3 + q3 + b4.w;
  const size_t rowoff = (size_t)r * HH;
  if (!final_layer) {
    ushort4 o;
    o.x = f2bf(fmaxf(h0, 0.f));
    o.y = f2bf(fmaxf(h1, 0.f));
    o.z = f2bf(fmaxf(h2, 0.f));
    o.w = f2bf(fmaxf(h3, 0.f));
    *(ushort4*)(Xb + rowoff + (lane << 2)) = o;
  } else {
    float mx = fmaxf(fmaxf(h0, h1), fmaxf(h2, h3));
#pragma unroll
    for (int off = 32; off >= 1; off >>= 1) mx = fmaxf(mx, __shfl_xor(mx, off));
    const float e0 = __expf(h0 - mx), e1 = __expf(h1 - mx);
    const float e2 = __expf(h2 - mx), e3 = __expf(h3 - mx);
    float s = e0 + e1 + e2 + e3;
#pragma unroll
    for (int off = 32; off >= 1; off >>= 1) s += __shfl_xor(s, off);
    const float inv = 1.0f / s;
    const float4 x0 = *(const float4*)(X0 + rowoff + (lane << 2));
    float4 o;
    o.x = e0 * inv + x0.x;
    o.y = e1 * inv + x0.y;
    o.z = e2 * inv + x0.z;
    o.w = e3 * inv + x0.w;
    *(float4*)(Xf + rowoff + (lane << 2)) = o;
  }
}

// ---------------------------------------------------------------------------
// Masked mean stage 1, (graph, chunk) blocks: load X chunk ONCE into LDS,
// loop the samples of this graph against it (X traffic 64MB -> 8MB).
__global__ __launch_bounds__(256) void mm_partial_kernel(
    const float* __restrict__ X, const int* __restrict__ graph,
    const void* __restrict__ mask, const int* __restrict__ flags,
    float* __restrict__ partial, float* __restrict__ cntbuf) {
  __shared__ float Xl[32][256];  // 32KB chunk
  const int c = blockIdx.x;      // chunk 0..31 (32 nodes)
  const int g = blockIdx.y;      // graph 0..7
  const int t = threadIdx.x;
  const int n0 = c * 32;
  const float* __restrict__ Xg = X + ((size_t)g * NN + n0) * HH;
#pragma unroll
  for (int i = 0; i < 8; ++i) {  // 2048 float4 / 256 threads
    const int fidx = i * 256 + t;
    const int row = fidx >> 6, c4 = fidx & 63;
    *(float4*)&Xl[row][c4 << 2] =
        *(const float4*)(Xg + (size_t)row * HH + (c4 << 2));
  }
  __syncthreads();
  const int mode = flags[0];
  for (int b = 0; b < BB; ++b) {
    if (graph[b] != g) continue;
    float a = 0.f;
    int cnt = 0;
    if (mode == 0) {
      const unsigned char* mb = (const unsigned char*)mask + (size_t)b * NN + n0;
      for (int n = 0; n < 32; ++n)
        if (mb[n]) { a += Xl[n][t]; cnt++; }
    } else if (mode == 1) {
      const int* mi = (const int*)mask + (size_t)b * NN + n0;
      for (int n = 0; n < 32; ++n)
        if (mi[n] != 0) { a += Xl[n][t]; cnt++; }
    } else {
      const float* mf = (const float*)mask + (size_t)b * NN + n0;
      for (int n = 0; n < 32; ++n)
        if (mf[n] != 0.0f) { a += Xl[n][t]; cnt++; }
    }
    partial[((size_t)b * NC + c) * HH + t] = a;
    if (t == 0) cntbuf[b * NC + c] = (float)cnt;
  }
}

__global__ __launch_bounds__(256) void mm_reduce_kernel(
    const float* __restrict__ partial, const float* __restrict__ cntbuf,
    float* __restrict__ out) {
  const int b = blockIdx.x, h = threadIdx.x;
  float s = 0.f;
#pragma unroll
  for (int c = 0; c < NC; ++c) s += partial[((size_t)b * NC + c) * HH + h];
  float cnt = 0.f;
#pragma unroll
  for (int c = 0; c < NC; ++c) cnt += cntbuf[b * NC + c];
  out[(size_t)b * HH + h] = s / fmaxf(cnt, 1.0f);
}

// ---------------------------------------------------------------------------
extern "C" void kernel_launch(void* const* d_in, const int* in_sizes, int n_in,
                              void* d_out, int out_size, void* d_ws,
                              size_t ws_size, hipStream_t stream) {
  const int* graph = (const int*)d_in[0];
  const void* mask = d_in[1];
  const float* xs = (const float*)d_in[2];    // [G][N][F] f32
  const float* As = (const float*)d_in[3];    // [G][N][N] f32
  const float* W_in = (const float*)d_in[4];  // [F][H] f32
  const float* b_in = (const float*)d_in[5];  // [H]
  const float* Ws = (const float*)d_in[6];    // [L][H][H] f32
  const float* bs = (const float*)d_in[7];    // [L][H]
  float* out = (float*)d_out;

  // Workspace: X(8M) | X0(8M) | Yb(4M) | Xb(4M) | xsb(2M) | WinT(64K)
  //          | WsT(512K) | ell(6M) | cnt(32K) | flags | partial(2M) | cntbuf
  float* X = (float*)d_ws;
  float* X0 = X + (size_t)MM * HH;
  unsigned short* Yb = (unsigned short*)(X0 + (size_t)MM * HH);
  unsigned short* Xb = Yb + (size_t)MM * HH;
  unsigned short* xsb = Xb + (size_t)MM * HH;
  unsigned short* WinT = xsb + (size_t)MM * FF;
  unsigned short* WsT = WinT + (size_t)HH * FF;
  uint2* ell = (uint2*)(WsT + (size_t)LL * HH * HH);
  int* cntArr = (int*)(ell + (size_t)MM * ELLCAP);
  int* flags = cntArr + MM;
  float* partial = (float*)(flags + 2);
  float* cntbuf = partial + (size_t)BB * NC * HH;

  // 1) prep: detect + xs convert + coalesced W transposes (1097 blocks)
  prep_kernel<<<1097, 256, 0, stream>>>((const uint4*)mask, flags,
                                        (const float4*)xs, (ushort4*)xsb, W_in,
                                        Ws, WinT, WsT);
  // 2) input GEMM (512 blocks) + ELL build (2048 blocks) in ONE dispatch
  stage2_kernel<<<2560, 256, 0, stream>>>(xsb, WinT, b_in, Xb, X0, As, ell,
                                          cntArr);
  // 3) L layers: GEMM (Xb @ WsT[l] -> Yb), SpMM (act(A@Yb+b) -> Xb / final X)
  for (int i = 0; i < LL; ++i) {
    layer_gemm_kernel<<<dim3(MM / 64, HH / 64), 256, 0, stream>>>(
        Xb, WsT + (size_t)i * HH * HH, Yb);
    spmm_ell_kernel<<<MM / 4, 256, 0, stream>>>(
        ell, cntArr, Yb, bs + (size_t)i * HH, X0, Xb, X, (i == LL - 1) ? 1 : 0);
  }
  // 4) masked mean: (graph, chunk) partials, then reduce
  mm_partial_kernel<<<dim3(NC, GG), 256, 0, stream>>>(X, graph, mask, flags,
                                                      partial, cntbuf);
  mm_reduce_kernel<<<BB, 256, 0, stream>>>(partial, cntbuf, out);
}

// Round 11
// 186.631 us; speedup vs baseline: 3.7056x; 1.1326x over previous
//
#include <hip/hip_runtime.h>
#include <hip/hip_bf16.h>

// Problem constants: G=8 graphs, N=1024 nodes, F=128 in-feat, H=256 hidden,
// L=4 layers, B=64 samples.
#define GG 8
#define NN 1024
#define FF 128
#define HH 256
#define LL 4
#define BB 64
#define MM (GG * NN)  // 8192 fused (g,n) rows
#define ELLCAP 96     // max nnz/row stored (binomial(1024,.02) max ~48)

typedef __attribute__((ext_vector_type(8))) short bf16x8_t;  // 8 bf16 = 4 VGPR
typedef __attribute__((ext_vector_type(4))) float f32x4_t;   // MFMA acc

__device__ inline unsigned short f2bf(float f) {
  union { float f; unsigned u; } c;
  c.f = f;
  unsigned r = (c.u + 0x7fffu + ((c.u >> 16) & 1u)) >> 16;  // RNE
  return (unsigned short)r;
}
__device__ inline float bf2f(unsigned short u) {
  union { unsigned u; float f; } c;
  c.u = (unsigned)u << 16;
  return c.f;
}

// ---------------------------------------------------------------------------
// prep (3145 blocks):
//   bx==0        : mask dtype sniff, single block, DIRECT flags[0]=mode write
//   [1,1025)     : xs f32 -> bf16 (262144 float4)
//   [1025,1097)  : coalesced 64x64-LDS-tile transposes of W_in (8) + Ws (64)
//   [1097,3145)  : ELL build, one wave per adjacency row (R5-validated body)
__global__ __launch_bounds__(256) void prep_kernel(
    const uint4* __restrict__ mask4, int* __restrict__ flags,
    const float4* __restrict__ xs4, ushort4* __restrict__ xsb4,
    const float* __restrict__ W_in, const float* __restrict__ Ws,
    unsigned short* __restrict__ WinT, unsigned short* __restrict__ WsT,
    const float* __restrict__ Adj, uint2* __restrict__ ell,
    int* __restrict__ cntArr) {
  __shared__ float Ld[64][65];
  __shared__ int df[2];
  const int bx = blockIdx.x;
  const int t = threadIdx.x;
  if (bx == 0) {
    // mode: 0 = 1-byte bool, 1 = int32 (0/1), 2 = float32
    if (t < 2) df[t] = 0;
    __syncthreads();
    int nonz = 0, isf = 0;
    for (int i = t; i < 4096; i += 256) {  // first 65536 bytes
      const uint4 v = mask4[i];
      const unsigned all = v.x | v.y | v.z | v.w;
      if (all & 0xFFFFFF00u) nonz = 1;
      if (((v.x >> 24) == 0x3fu) || ((v.y >> 24) == 0x3fu) ||
          ((v.z >> 24) == 0x3fu) || ((v.w >> 24) == 0x3fu))
        isf = 1;
    }
    if (nonz) atomicOr(&df[0], 1);
    if (isf) atomicOr(&df[1], 1);
    __syncthreads();
    if (t == 0) flags[0] = df[1] ? 2 : (df[0] ? 0 : 1);
  } else if (bx < 1025) {
    const int i = (bx - 1) * 256 + t;
    const float4 v = xs4[i];
    ushort4 o;
    o.x = f2bf(v.x); o.y = f2bf(v.y); o.z = f2bf(v.z); o.w = f2bf(v.w);
    xsb4[i] = o;
  } else if (bx < 1097) {
    int tt = bx - 1025;
    const float* src;
    unsigned short* dst;
    int R, C, r0, c0;
    if (tt < 8) {  // W_in [128][256] -> WinT [256][128]
      src = W_in; dst = WinT; R = FF; C = HH;
      r0 = (tt >> 2) * 64; c0 = (tt & 3) * 64;
    } else {       // Ws[l] [256][256] -> WsT[l] [256][256]
      tt -= 8;
      const int l = tt >> 4, rem = tt & 15;
      src = Ws + (size_t)l * HH * HH;
      dst = WsT + (size_t)l * HH * HH;
      R = HH; C = HH;
      r0 = (rem >> 2) * 64; c0 = (rem & 3) * 64;
    }
#pragma unroll
    for (int i = 0; i < 16; ++i) {  // coalesced read
      const int idx = i * 256 + t;
      const int r = idx >> 6, c = idx & 63;
      Ld[r][c] = src[(size_t)(r0 + r) * C + c0 + c];
    }
    __syncthreads();
#pragma unroll
    for (int i = 0; i < 16; ++i) {  // coalesced transposed write
      const int idx = i * 256 + t;
      const int cc = idx >> 6, rr = idx & 63;
      dst[(size_t)(c0 + cc) * R + r0 + rr] = f2bf(Ld[rr][cc]);
    }
  } else {
    const int lane = t & 63;
    const int wid = t >> 6;
    const int r = (bx - 1097) * 4 + wid;  // 0..8191
    const float* __restrict__ Arow = Adj + (size_t)r * NN;
    int cnt = 0;
    for (int mc = 0; mc < NN; mc += 64) {
      const float a = Arow[mc + lane];
      const unsigned long long bal = __ballot(a != 0.0f);
      if (a != 0.0f) {
        const int pos = cnt + __popcll(bal & ((1ULL << lane) - 1ULL));
        if (pos < ELLCAP) {
          uint2 e;
          e.x = __float_as_uint(a);
          e.y = (unsigned)(mc + lane);
          ell[(size_t)r * ELLCAP + pos] = e;
        }
      }
      cnt += __popcll(bal);
    }
    if (lane == 0) cntArr[r] = min(cnt, ELLCAP);
  }
}

// ---------------------------------------------------------------------------
// bf16 MFMA GEMM (R5-validated, byte-identical): C = A[M][K] @ BT[HH][K]^T.
// 64x64 tile, 4 waves (2x2 of 32x32), whole K staged in LDS once,
// XOR-swizzle (slot k ^= row&7). FUSED: +bias, relu, bf16 Cb AND f32 Cf.
template <int K, bool FUSED>
__global__ __launch_bounds__(256) void mfma_gemm_kernel(
    const unsigned short* __restrict__ A, const unsigned short* __restrict__ BT,
    const float* __restrict__ bias, unsigned short* __restrict__ Cb,
    float* __restrict__ Cf) {
  constexpr int KS = K / 8;  // 16B slots per row
  __shared__ uint4 As4[64 * KS];
  __shared__ uint4 Bs4[64 * KS];
  const int t = threadIdx.x;
  const int lane = t & 63;
  const int w = t >> 6;
  const int wm = (w >> 1) * 32;
  const int wn = (w & 1) * 32;
  const int m0 = blockIdx.x * 64;
  const int n0 = blockIdx.y * 64;
  const int lk = lane >> 4;
  const int lr = lane & 15;
  const uint4* __restrict__ Ag = (const uint4*)(A + (size_t)m0 * K);
  const uint4* __restrict__ Bg = (const uint4*)(BT + (size_t)n0 * K);
#pragma unroll
  for (int it = 0; it < K / 32; ++it) {
    const int c = it * 256 + t;
    const int row = c / KS;
    const int k = c % KS;
    const int slot = row * KS + (k ^ (row & 7));
    As4[slot] = Ag[c];
    Bs4[slot] = Bg[c];
  }
  __syncthreads();
  f32x4_t acc[2][2] = {};
#pragma unroll
  for (int ks = 0; ks < K / 32; ++ks) {
    const int q = ks * 4 + lk;
    const int ra0 = wm + lr, ra1 = wm + 16 + lr;
    const int rb0 = wn + lr, rb1 = wn + 16 + lr;
    const bf16x8_t a0 = *(const bf16x8_t*)(&As4[ra0 * KS + (q ^ (ra0 & 7))]);
    const bf16x8_t a1 = *(const bf16x8_t*)(&As4[ra1 * KS + (q ^ (ra1 & 7))]);
    const bf16x8_t b0 = *(const bf16x8_t*)(&Bs4[rb0 * KS + (q ^ (rb0 & 7))]);
    const bf16x8_t b1 = *(const bf16x8_t*)(&Bs4[rb1 * KS + (q ^ (rb1 & 7))]);
    acc[0][0] = __builtin_amdgcn_mfma_f32_16x16x32_bf16(a0, b0, acc[0][0], 0, 0, 0);
    acc[0][1] = __builtin_amdgcn_mfma_f32_16x16x32_bf16(a0, b1, acc[0][1], 0, 0, 0);
    acc[1][0] = __builtin_amdgcn_mfma_f32_16x16x32_bf16(a1, b0, acc[1][0], 0, 0, 0);
    acc[1][1] = __builtin_amdgcn_mfma_f32_16x16x32_bf16(a1, b1, acc[1][1], 0, 0, 0);
  }
#pragma unroll
  for (int rg = 0; rg < 2; ++rg)
#pragma unroll
    for (int cg = 0; cg < 2; ++cg)
#pragma unroll
      for (int j = 0; j < 4; ++j) {
        // verified C/D layout: col = lane&15, row = (lane>>4)*4 + reg
        const int row = m0 + wm + rg * 16 + (lane >> 4) * 4 + j;
        const int col = n0 + wn + cg * 16 + lr;
        float v = acc[rg][cg][j];
        if (FUSED) {
          v += bias[col];
          v = fmaxf(v, 0.0f);
          Cb[(size_t)row * HH + col] = f2bf(v);
          Cf[(size_t)row * HH + col] = v;
        } else {
          Cb[(size_t)row * HH + col] = f2bf(v);
        }
      }
}

// ---------------------------------------------------------------------------
// ELL SpMM (R5-validated, byte-identical): X = act(A @ Yb + bias). One wave
// per row; lane owns cols lane*4..+3; 2-way unrolled gather loop.
// Non-final: relu -> bf16 Xb. Final: softmax + residual X0 -> f32 Xf.
__global__ __launch_bounds__(256) void spmm_ell_kernel(
    const uint2* __restrict__ ell, const int* __restrict__ cntArr,
    const unsigned short* __restrict__ Yb, const float* __restrict__ bias,
    const float* __restrict__ X0, unsigned short* __restrict__ Xb,
    float* __restrict__ Xf, int final_layer) {
  const int lane = threadIdx.x & 63;
  const int wid = threadIdx.x >> 6;
  const int r = blockIdx.x * 4 + wid;  // 0..8191
  const int g = r >> 10;
  const unsigned short* __restrict__ Yg = Yb + (size_t)g * NN * HH;
  const int cnt = cntArr[r];
  const uint2* __restrict__ erow = ell + (size_t)r * ELLCAP;
  float p0 = 0.f, p1 = 0.f, p2 = 0.f, p3 = 0.f;
  float q0 = 0.f, q1 = 0.f, q2 = 0.f, q3 = 0.f;
  for (int base = 0; base < cnt; base += 64) {
    const int m = min(64, cnt - base);
    const uint2 e = erow[base + ((lane < m) ? lane : 0)];
    int j = 0;
    for (; j + 2 <= m; j += 2) {
      const float v0 = __uint_as_float(__shfl(e.x, j));
      const int i0 = (int)__shfl(e.y, j);
      const float v1 = __uint_as_float(__shfl(e.x, j + 1));
      const int i1 = (int)__shfl(e.y, j + 1);
      const ushort4 y0 = *(const ushort4*)(Yg + (size_t)i0 * HH + (lane << 2));
      const ushort4 y1 = *(const ushort4*)(Yg + (size_t)i1 * HH + (lane << 2));
      p0 += v0 * bf2f(y0.x); p1 += v0 * bf2f(y0.y);
      p2 += v0 * bf2f(y0.z); p3 += v0 * bf2f(y0.w);
      q0 += v1 * bf2f(y1.x); q1 += v1 * bf2f(y1.y);
      q2 += v1 * bf2f(y1.z); q3 += v1 * bf2f(y1.w);
    }
    if (j < m) {
      const float v0 = __uint_as_float(__shfl(e.x, j));
      const int i0 = (int)__shfl(e.y, j);
      const ushort4 y0 = *(const ushort4*)(Yg + (size_t)i0 * HH + (lane << 2));
      p0 += v0 * bf2f(y0.x); p1 += v0 * bf2f(y0.y);
      p2 += v0 * bf2f(y0.z); p3 += v0 * bf2f(y0.w);
    }
  }
  const float4 b4 = *(const float4*)(bias + (lane << 2));
  const float h0 = p0 + q0 + b4.x, h1 = p1 + q1 + b4.y;
  const float h2 = p2 + q2 + b4.z, h3 = p3 + q3 + b4.w;
  const size_t rowoff = (size_t)r * HH;
  if (!final_layer) {
    ushort4 o;
    o.x = f2bf(fmaxf(h0, 0.f));
    o.y = f2bf(fmaxf(h1, 0.f));
    o.z = f2bf(fmaxf(h2, 0.f));
    o.w = f2bf(fmaxf(h3, 0.f));
    *(ushort4*)(Xb + rowoff + (lane << 2)) = o;
  } else {
    float mx = fmaxf(fmaxf(h0, h1), fmaxf(h2, h3));
#pragma unroll
    for (int off = 32; off >= 1; off >>= 1) mx = fmaxf(mx, __shfl_xor(mx, off));
    const float e0 = __expf(h0 - mx), e1 = __expf(h1 - mx);
    const float e2 = __expf(h2 - mx), e3 = __expf(h3 - mx);
    float s = e0 + e1 + e2 + e3;
#pragma unroll
    for (int off = 32; off >= 1; off >>= 1) s += __shfl_xor(s, off);
    const float inv = 1.0f / s;
    const float4 x0 = *(const float4*)(X0 + rowoff + (lane << 2));
    float4 o;
    o.x = e0 * inv + x0.x;
    o.y = e1 * inv + x0.y;
    o.z = e2 * inv + x0.z;
    o.w = e3 * inv + x0.w;
    *(float4*)(Xf + rowoff + (lane << 2)) = o;
  }
}

// ---------------------------------------------------------------------------
// Masked mean, stage 1 (R5-validated): grid (16 chunks x 64 samples).
__global__ __launch_bounds__(256) void mm_partial_kernel(
    const float* __restrict__ X, const int* __restrict__ graph,
    const void* __restrict__ mask, const int* __restrict__ flags,
    float* __restrict__ partial, float* __restrict__ cntbuf) {
  __shared__ unsigned char m[64];
  const int c = blockIdx.x;
  const int b = blockIdx.y;
  const int h = threadIdx.x;
  const int n0 = c * 64;
  const int mode = flags[0];
  if (h < 64) {
    const int n = n0 + h;
    bool on;
    if (mode == 1) on = ((const int*)mask)[(size_t)b * NN + n] != 0;
    else if (mode == 2) on = ((const float*)mask)[(size_t)b * NN + n] != 0.0f;
    else on = ((const unsigned char*)mask)[(size_t)b * NN + n] != 0;
    m[h] = on ? 1 : 0;
  }
  __syncthreads();
  const int g = graph[b];
  const float* __restrict__ Xg = X + ((size_t)g * NN + n0) * HH;
  float a0 = 0.f, a1 = 0.f, a2 = 0.f, a3 = 0.f;
  int c0 = 0, c1 = 0, c2 = 0, c3 = 0;
#pragma unroll 4
  for (int n = 0; n < 16; ++n) {
    if (m[n])      { a0 += Xg[(size_t)n * HH + h]; c0++; }
    if (m[n + 16]) { a1 += Xg[(size_t)(n + 16) * HH + h]; c1++; }
    if (m[n + 32]) { a2 += Xg[(size_t)(n + 32) * HH + h]; c2++; }
    if (m[n + 48]) { a3 += Xg[(size_t)(n + 48) * HH + h]; c3++; }
  }
  partial[((size_t)b * 16 + c) * HH + h] = (a0 + a1) + (a2 + a3);
  if (h == 0) cntbuf[b * 16 + c] = (float)((c0 + c1) + (c2 + c3));
}

__global__ __launch_bounds__(256) void mm_reduce_kernel(
    const float* __restrict__ partial, const float* __restrict__ cntbuf,
    float* __restrict__ out) {
  const int b = blockIdx.x, h = threadIdx.x;
  float s = 0.f;
#pragma unroll
  for (int c = 0; c < 16; ++c) s += partial[((size_t)b * 16 + c) * HH + h];
  float cnt = 0.f;
#pragma unroll
  for (int c = 0; c < 16; ++c) cnt += cntbuf[b * 16 + c];
  out[(size_t)b * HH + h] = s / fmaxf(cnt, 1.0f);
}

// ---------------------------------------------------------------------------
extern "C" void kernel_launch(void* const* d_in, const int* in_sizes, int n_in,
                              void* d_out, int out_size, void* d_ws,
                              size_t ws_size, hipStream_t stream) {
  const int* graph = (const int*)d_in[0];
  const void* mask = d_in[1];
  const float* xs = (const float*)d_in[2];    // [G][N][F] f32
  const float* As = (const float*)d_in[3];    // [G][N][N] f32
  const float* W_in = (const float*)d_in[4];  // [F][H] f32
  const float* b_in = (const float*)d_in[5];  // [H]
  const float* Ws = (const float*)d_in[6];    // [L][H][H] f32
  const float* bs = (const float*)d_in[7];    // [L][H]
  float* out = (float*)d_out;

  // Workspace: X(8M) | X0(8M) | Yb(4M) | Xb(4M) | xsb(2M) | WinT(64K)
  //          | WsT(512K) | ell(6M) | cnt(32K) | flags | partial(1M) | cntbuf
  float* X = (float*)d_ws;
  float* X0 = X + (size_t)MM * HH;
  unsigned short* Yb = (unsigned short*)(X0 + (size_t)MM * HH);
  unsigned short* Xb = Yb + (size_t)MM * HH;
  unsigned short* xsb = Xb + (size_t)MM * HH;
  unsigned short* WinT = xsb + (size_t)MM * FF;
  unsigned short* WsT = WinT + (size_t)HH * FF;
  uint2* ell = (uint2*)(WsT + (size_t)LL * HH * HH);
  int* cntArr = (int*)(ell + (size_t)MM * ELLCAP);
  int* flags = cntArr + MM;
  float* partial = (float*)(flags + 2);
  float* cntbuf = partial + (size_t)BB * 16 * HH;

  // 1) prep: detect + xs convert + coalesced W transpose + ELL (3145 blocks)
  prep_kernel<<<3145, 256, 0, stream>>>((const uint4*)mask, flags,
                                        (const float4*)xs, (ushort4*)xsb, W_in,
                                        Ws, WinT, WsT, As, ell, cntArr);

  const dim3 grd(MM / 64, HH / 64);
  // 2) X0 (f32) and Xb (bf16) = relu(xs @ W_in + b_in) — once per graph
  mfma_gemm_kernel<FF, true><<<grd, 256, 0, stream>>>(xsb, WinT, b_in, Xb, X0);
  for (int i = 0; i < LL; ++i) {
    // Yb = Xb @ Ws[i]  (bf16 out)
    mfma_gemm_kernel<HH, false><<<grd, 256, 0, stream>>>(
        Xb, WsT + (size_t)i * HH * HH, nullptr, Yb, nullptr);
    // X = act(A @ Yb + bs[i]); final: softmax + residual -> f32 X
    spmm_ell_kernel<<<MM / 4, 256, 0, stream>>>(
        ell, cntArr, Yb, bs + (size_t)i * HH, X0, Xb, X, (i == LL - 1) ? 1 : 0);
  }
  // 3) masked mean
  mm_partial_kernel<<<dim3(16, BB), 256, 0, stream>>>(X, graph, mask, flags,
                                                      partial, cntbuf);
  mm_reduce_kernel<<<BB, 256, 0, stream>>>(partial, cntbuf, out);
}